// Round 4
// baseline (173.982 us; speedup 1.0000x reference)
//
#include <hip/hip_runtime.h>
#include <hip/hip_bf16.h>

#define NN 8192
#define FIN 512
#define FOUT 256
#define FH 64                 // head-mean output cols
#define JSPLIT 16
#define JCHUNK (NN / JSPLIT)  // 512
#define STEPS (JCHUNK / 32)   // 16

typedef float f32x16 __attribute__((ext_vector_type(16)));
typedef short bf16x8 __attribute__((ext_vector_type(8)));
typedef unsigned short us8 __attribute__((ext_vector_type(8)));

static __device__ __forceinline__ unsigned short f2bf(float x) {
  unsigned int u = __builtin_bit_cast(unsigned int, x);
  unsigned int r = (u + 0x7fffu + ((u >> 16) & 1u)) >> 16;  // RNE
  return (unsigned short)r;
}
static __device__ __forceinline__ float bf2f(unsigned short u) {
  unsigned int v = ((unsigned int)u) << 16;
  return __builtin_bit_cast(float, v);
}
static __device__ __forceinline__ float fastexp2(float x) {
  float r;
  asm("v_exp_f32 %0, %1" : "=v"(r) : "v"(x));
  return r;
}

// ---- K1: prep_small — fold head-mean + attention vecs into W fragments ----
// Bw layout: [kt(32)][h(2)][nf(3)][kh(2)][n(32)][e(8)] bf16 (192 KB).
// nf<2: Wm[k][nf*32+n] (quarter-summed heads); nf=2: n==0 -> w~s, n==1 -> w~d
// (both pre-scaled by log2(e)), else 0.
__global__ __launch_bounds__(256) void prep_small(const float* __restrict__ W,
                                                  const float* __restrict__ a,
                                                  unsigned short* __restrict__ Bw) {
  const int kt = blockIdx.x;  // 0..31
  __shared__ float wm[16][64];
  __shared__ float wt[16][2];
  const int t = threadIdx.x;
#pragma unroll
  for (int i = 0; i < 4; ++i) {
    const int idx = t + i * 256;
    const int kr = idx >> 6, c = idx & 63;
    const float* wr = W + (size_t)(kt * 16 + kr) * FOUT + c;
    wm[kr][c] = 0.25f * (wr[0] + wr[64] + wr[128] + wr[192]);
  }
  if (t < 32) {
    const int kr = t & 15, sel = t >> 4;
    const float* wr = W + (size_t)(kt * 16 + kr) * FOUT;
    const float* av = a + sel * FOUT;
    float s = 0.f;
    for (int n = 0; n < FOUT; ++n) s += wr[n] * av[n];
    wt[kr][sel] = s * 1.44269504f;
  }
  __syncthreads();
#pragma unroll
  for (int i = 0; i < 12; ++i) {
    const int idx = t + i * 256;  // within-kt offset < 3072
    const int e = idx & 7, n = (idx >> 3) & 31, r2 = idx >> 8;
    const int khb = r2 & 1, q = r2 >> 1;
    const int nf = q % 3, h = q / 3;
    const int k = khb * 8 + e;
    float v = nf < 2 ? wm[k][nf * 32 + n]
                     : (n == 0 ? wt[k][0] : (n == 1 ? wt[k][1] : 0.f));
    const unsigned short hi = f2bf(v);
    Bw[(size_t)kt * 3072 + idx] = (h == 0) ? hi : f2bf(v - bf2f(hi));
  }
}

// ---- K2: convert_x — x f32 -> hi/lo bf16 A-fragments ----
// xf frag index = (((mw*32+kt)*2+h)*2+kh)*32 + r, 8 shorts each (16 MB).
__global__ __launch_bounds__(256) void convert_x(const float* __restrict__ X,
                                                 unsigned short* __restrict__ xf) {
  const int f = blockIdx.x * 256 + threadIdx.x;  // < 524288
  const int r = f & 31, kh = (f >> 5) & 1, kt = (f >> 6) & 31, mw = f >> 11;
  const float* src = X + (size_t)(mw * 32 + r) * FIN + kt * 16 + kh * 8;
  const float4 v0 = *(const float4*)src;
  const float4 v1 = *(const float4*)(src + 4);
  const float vv[8] = {v0.x, v0.y, v0.z, v0.w, v1.x, v1.y, v1.z, v1.w};
  us8 vh, vl;
#pragma unroll
  for (int e = 0; e < 8; ++e) {
    const unsigned short hi = f2bf(vv[e]);
    vh[e] = hi;
    vl[e] = f2bf(vv[e] - bf2f(hi));
  }
  const size_t b0 = ((size_t)(mw * 32 + kt) * 4 + kh) * 256 + (size_t)r * 8;
  *(us8*)(xf + b0) = vh;
  *(us8*)(xf + b0 + 512) = vl;  // h stride = 512 shorts
}

// ---- K3: gemm_whm — Whm = x @ Wm (hi/lo 3-product MFMA) + s extraction ----
// 256 blocks x 192 thr (3 waves = nf 0,1,2). No main-loop LDS/barriers.
__global__ __launch_bounds__(192) void gemm_whm(const unsigned short* __restrict__ xf,
                                                const unsigned short* __restrict__ Bw,
                                                float* __restrict__ Whm,
                                                float* __restrict__ ssrc,
                                                float* __restrict__ sdst) {
  __shared__ float sred[32][2];
  const int mw = blockIdx.x;
  const int nf = threadIdx.x >> 6, lane = threadIdx.x & 63;
  const int l31 = lane & 31, kh = lane >> 5;
  f32x16 acc = (f32x16)(0.f);
  const unsigned short* ap = xf + ((size_t)(mw * 32) * 4 + kh) * 256 + l31 * 8;
  const unsigned short* bp = Bw + ((size_t)nf * 2 + kh) * 256 + l31 * 8;
#pragma unroll 4
  for (int kt = 0; kt < 32; ++kt) {
    const bf16x8 a_h = *(const bf16x8*)(ap + kt * 1024);
    const bf16x8 a_l = *(const bf16x8*)(ap + kt * 1024 + 512);
    const bf16x8 b_h = *(const bf16x8*)(bp + kt * 3072);
    const bf16x8 b_l = *(const bf16x8*)(bp + kt * 3072 + 1536);
    acc = __builtin_amdgcn_mfma_f32_32x32x16_bf16(a_h, b_h, acc, 0, 0, 0);
    acc = __builtin_amdgcn_mfma_f32_32x32x16_bf16(a_h, b_l, acc, 0, 0, 0);
    acc = __builtin_amdgcn_mfma_f32_32x32x16_bf16(a_l, b_h, acc, 0, 0, 0);
  }
  if (nf < 2) {
#pragma unroll
    for (int reg = 0; reg < 16; ++reg) {
      const int row = (reg & 3) + ((reg >> 2) << 3) + (kh << 2);
      Whm[(size_t)(mw * 32 + row) * FH + nf * 32 + l31] = acc[reg];
    }
  } else if (l31 < 2) {
#pragma unroll
    for (int reg = 0; reg < 16; ++reg) {
      const int row = (reg & 3) + ((reg >> 2) << 3) + (kh << 2);
      sred[row][l31] = acc[reg];
    }
  }
  __syncthreads();
  if (threadIdx.x < 32) {
    ssrc[mw * 32 + threadIdx.x] = sred[threadIdx.x][0];
    sdst[mw * 32 + threadIdx.x] = sred[threadIdx.x][1];
  }
}

// ---- K4: build_whb — Whm f32 -> Bg hi/lo B-fragments for gat_aggr ----
// Bg per jw (32 j): [h(2)][kc(2)][khb(2)][nf(2)][nn(32)][e(8)] = 4096 shorts.
__global__ __launch_bounds__(256) void build_whb(const float* __restrict__ Whm,
                                                 unsigned short* __restrict__ Bg) {
  const int idx = blockIdx.x * 256 + threadIdx.x;  // < 65536
  const int n = idx & 63, jo = idx >> 6;           // jo = j>>3 < 1024
  const int jw = jo >> 2, kc = (jo >> 1) & 1, khb = jo & 1;
  const int nf = n >> 5, nn = n & 31;
  us8 vh, vl;
#pragma unroll
  for (int e = 0; e < 8; ++e) {
    const float v = Whm[(size_t)(jo * 8 + e) * FH + n];
    const unsigned short hi = f2bf(v);
    vh[e] = hi;
    vl[e] = f2bf(v - bf2f(hi));
  }
  const size_t base =
      (size_t)jw * 4096 + (size_t)((kc * 2 + khb) * 2 + nf) * 256 + nn * 8;
  *(us8*)(Bg + base) = vh;           // h=0
  *(us8*)(Bg + base + 2048) = vl;    // h=1
}

// ---- K5: gat_aggr — barrier-free fused aggregation, B direct from L2 ----
#define GEN1(V, E, Q, SD)                         \
  {                                               \
    float tt = ss + (SD);                         \
    float lr = fmaxf(tt, 0.2f * tt);              \
    float pe = (Q) ? fastexp2(lr) : 1.0f;         \
    unsigned short hb = f2bf(pe);                 \
    V[E] = (short)hb;                             \
    dacc += bf2f(hb);                             \
  }
#define GEN8(V, QA, QB, SA, SB)                   \
  GEN1(V, 0, (QA).x, (SA).x)                      \
  GEN1(V, 1, (QA).y, (SA).y)                      \
  GEN1(V, 2, (QA).z, (SA).z)                      \
  GEN1(V, 3, (QA).w, (SA).w)                      \
  GEN1(V, 4, (QB).x, (SB).x)                      \
  GEN1(V, 5, (QB).y, (SB).y)                      \
  GEN1(V, 6, (QB).z, (SB).z)                      \
  GEN1(V, 7, (QB).w, (SB).w)

__global__ __launch_bounds__(256, 4) void gat_aggr(
    const int* __restrict__ adj, const float* __restrict__ ssrc_g,
    const float* __restrict__ sdst_g, const unsigned short* __restrict__ Bg,
    float* __restrict__ Up, float* __restrict__ Dp) {
  const int bid = blockIdx.x;
  const int bj = bid & 15, bm = bid >> 4;
  const int wv = threadIdx.x >> 6, lane = threadIdx.x & 63;
  const int l31 = lane & 31, kh = lane >> 5;
  const int rbase = bm * 128;
  const int myrow = rbase + wv * 32 + l31;
  const int jb = bj * JCHUNK;
  const float ss = ssrc_g[myrow];
  const int* arow = adj + (size_t)myrow * NN + jb + kh * 8;
  const float* sdp = sdst_g + jb + kh * 8;
  // B frag base: + t*4096 + h*2048 + kc*1024 + nf*256
  const unsigned short* bbase =
      Bg + (size_t)(bj * 16) * 4096 + kh * 512 + l31 * 8;

  f32x16 acc0 = (f32x16)(0.f), acc1 = (f32x16)(0.f);
  float dacc = 0.f;

  int4 ajA0 = *(const int4*)(arow);
  int4 ajA1 = *(const int4*)(arow + 4);
  int4 ajA2 = *(const int4*)(arow + 16);
  int4 ajA3 = *(const int4*)(arow + 20);
  int4 ajB0, ajB1, ajB2, ajB3;

#define STEP(T, C0, C1, C2, C3, N0, N1, N2, N3)                               \
  {                                                                           \
    const unsigned short* tb = bbase + (size_t)(T) * 4096;                    \
    const bf16x8 b00 = *(const bf16x8*)(tb);          /* kc0 h0 nf0 */        \
    const bf16x8 b01 = *(const bf16x8*)(tb + 2048);   /* kc0 h1 nf0 */        \
    const bf16x8 b02 = *(const bf16x8*)(tb + 256);    /* kc0 h0 nf1 */        \
    const bf16x8 b03 = *(const bf16x8*)(tb + 2304);   /* kc0 h1 nf1 */        \
    const bf16x8 b10 = *(const bf16x8*)(tb + 1024);   /* kc1 h0 nf0 */        \
    const bf16x8 b11 = *(const bf16x8*)(tb + 3072);   /* kc1 h1 nf0 */        \
    const bf16x8 b12 = *(const bf16x8*)(tb + 1280);   /* kc1 h0 nf1 */        \
    const bf16x8 b13 = *(const bf16x8*)(tb + 3328);   /* kc1 h1 nf1 */        \
    if ((T) + 1 < STEPS) {                                                    \
      N0 = *(const int4*)(arow + ((T) + 1) * 32);                             \
      N1 = *(const int4*)(arow + ((T) + 1) * 32 + 4);                         \
      N2 = *(const int4*)(arow + ((T) + 1) * 32 + 16);                        \
      N3 = *(const int4*)(arow + ((T) + 1) * 32 + 20);                        \
    }                                                                         \
    bf16x8 af0, af1;                                                          \
    {                                                                         \
      const float4 sA0 = *(const float4*)(sdp + (T) * 32);                    \
      const float4 sB0 = *(const float4*)(sdp + (T) * 32 + 4);                \
      const float4 sA1 = *(const float4*)(sdp + (T) * 32 + 16);               \
      const float4 sB1 = *(const float4*)(sdp + (T) * 32 + 20);               \
      GEN8(af0, C0, C1, sA0, sB0);                                            \
      GEN8(af1, C2, C3, sA1, sB1);                                            \
    }                                                                         \
    acc0 = __builtin_amdgcn_mfma_f32_32x32x16_bf16(af0, b00, acc0, 0, 0, 0);  \
    acc0 = __builtin_amdgcn_mfma_f32_32x32x16_bf16(af0, b01, acc0, 0, 0, 0);  \
    acc1 = __builtin_amdgcn_mfma_f32_32x32x16_bf16(af0, b02, acc1, 0, 0, 0);  \
    acc1 = __builtin_amdgcn_mfma_f32_32x32x16_bf16(af0, b03, acc1, 0, 0, 0);  \
    acc0 = __builtin_amdgcn_mfma_f32_32x32x16_bf16(af1, b10, acc0, 0, 0, 0);  \
    acc0 = __builtin_amdgcn_mfma_f32_32x32x16_bf16(af1, b11, acc0, 0, 0, 0);  \
    acc1 = __builtin_amdgcn_mfma_f32_32x32x16_bf16(af1, b12, acc1, 0, 0, 0);  \
    acc1 = __builtin_amdgcn_mfma_f32_32x32x16_bf16(af1, b13, acc1, 0, 0, 0);  \
  }

#pragma unroll 1
  for (int it = 0; it < STEPS / 2; ++it) {
    STEP(2 * it, ajA0, ajA1, ajA2, ajA3, ajB0, ajB1, ajB2, ajB3)
    STEP(2 * it + 1, ajB0, ajB1, ajB2, ajB3, ajA0, ajA1, ajA2, ajA3)
  }
#undef STEP

  // ---- D: lanes l, l+32 hold complementary kh halves of same row ----
  dacc += __shfl_xor(dacc, 32);
  if (lane < 32) Dp[(size_t)bj * NN + myrow] = dacc;

  // ---- U: C/D layout col=lane&31, row=(reg&3)+8*(reg>>2)+4*(lane>>5) ----
  float* ub = Up + ((size_t)bj * NN + rbase + wv * 32) * FH;
#pragma unroll
  for (int reg = 0; reg < 16; ++reg) {
    const int rr = (reg & 3) + ((reg >> 2) << 3) + (kh << 2);
    ub[(size_t)rr * FH + l31] = acc0[reg];
    ub[(size_t)rr * FH + 32 + l31] = acc1[reg];
  }
}

// ---- K6: finalize — combine j-splits, divide ----
__global__ __launch_bounds__(256) void finalize(const float* __restrict__ Up,
                                                const float* __restrict__ Dp,
                                                float* __restrict__ out) {
  const int idx = blockIdx.x * 256 + threadIdx.x;  // < 8192*64
  const int i = idx >> 6;
  float u = 0.f, d = 0.f;
#pragma unroll
  for (int s = 0; s < JSPLIT; ++s) {
    d += Dp[(size_t)s * NN + i];
    u += Up[(size_t)s * NN * FH + idx];
  }
  out[idx] = u / d;
}

extern "C" void kernel_launch(void* const* d_in, const int* in_sizes, int n_in,
                              void* d_out, int out_size, void* d_ws, size_t ws_size,
                              hipStream_t stream) {
  const float* x = (const float*)d_in[0];
  const int* adj = (const int*)d_in[1];
  const float* W = (const float*)d_in[2];
  const float* a = (const float*)d_in[3];
  char* ws = (char*)d_ws;

  // ws layout (~37 MB):
  //   xf   [0, 16 MB)   bf16 hi/lo x-fragments (dead after gemm_whm)
  //   Up   [0, 32 MB)   f32 U partials -- OVERLAPS xf (sequential lifetime)
  //   Bg   [32, 34 MB)  bf16 hi/lo Whm B-fragments
  //   Whm  [34, 36 MB)  f32 head-mean of Wh
  //   Bw   [36 MB, +192 KB)  W fragments; then ssrc/sdst/Dp
  unsigned short* xf = (unsigned short*)ws;
  float* Up = (float*)ws;
  unsigned short* Bg = (unsigned short*)(ws + ((size_t)32 << 20));
  float* Whm = (float*)(ws + ((size_t)34 << 20));
  unsigned short* Bw = (unsigned short*)(ws + ((size_t)36 << 20));
  float* ssrc = (float*)(ws + ((size_t)36 << 20) + (256u << 10));
  float* sdst = (float*)(ws + ((size_t)36 << 20) + (288u << 10));
  float* Dp = (float*)(ws + ((size_t)36 << 20) + (320u << 10));
  float* out = (float*)d_out;

  prep_small<<<32, 256, 0, stream>>>(W, a, Bw);
  convert_x<<<2048, 256, 0, stream>>>(x, xf);
  gemm_whm<<<256, 192, 0, stream>>>(xf, Bw, Whm, ssrc, sdst);
  build_whb<<<65536 / 256, 256, 0, stream>>>(Whm, Bg);
  gat_aggr<<<64 * JSPLIT, 256, 0, stream>>>(adj, ssrc, sdst, Bg, Up, Dp);
  finalize<<<NN * FH / 256, 256, 0, stream>>>(Up, Dp, out);
}

// Round 5
// 158.629 us; speedup vs baseline: 1.0968x; 1.0968x over previous
//
#include <hip/hip_runtime.h>
#include <hip/hip_bf16.h>

#define NN 8192
#define FIN 512
#define FOUT 256
#define FH 64                 // head-mean output cols
#define JSPLIT 32
#define JCHUNK (NN / JSPLIT)  // 256
#define STEPS (JCHUNK / 32)   // 8

typedef float f32x16 __attribute__((ext_vector_type(16)));
typedef short bf16x8 __attribute__((ext_vector_type(8)));
typedef unsigned short us8 __attribute__((ext_vector_type(8)));

static __device__ __forceinline__ unsigned short f2bf(float x) {
  unsigned int u = __builtin_bit_cast(unsigned int, x);
  unsigned int r = (u + 0x7fffu + ((u >> 16) & 1u)) >> 16;  // RNE
  return (unsigned short)r;
}
static __device__ __forceinline__ float bf2f(unsigned short u) {
  unsigned int v = ((unsigned int)u) << 16;
  return __builtin_bit_cast(float, v);
}
static __device__ __forceinline__ float fastexp2(float x) {
  float r;
  asm("v_exp_f32 %0, %1" : "=v"(r) : "v"(x));
  return r;
}

// ---- K1: prep_small — fold head-mean + attention vecs into W fragments ----
// Bw layout: [kt(32)][h(2)][nf(3)][kh(2)][n(32)][e(8)] bf16 (192 KB).
// nf<2: Wm[k][nf*32+n] (quarter-summed heads); nf=2: n==0 -> w~s, n==1 -> w~d
// (both pre-scaled by log2(e)), else 0.
__global__ __launch_bounds__(256) void prep_small(const float* __restrict__ W,
                                                  const float* __restrict__ a,
                                                  unsigned short* __restrict__ Bw) {
  const int kt = blockIdx.x;  // 0..31
  __shared__ float wm[16][64];
  __shared__ float wt[16][2];
  const int t = threadIdx.x;
#pragma unroll
  for (int i = 0; i < 4; ++i) {
    const int idx = t + i * 256;
    const int kr = idx >> 6, c = idx & 63;
    const float* wr = W + (size_t)(kt * 16 + kr) * FOUT + c;
    wm[kr][c] = 0.25f * (wr[0] + wr[64] + wr[128] + wr[192]);
  }
  if (t < 32) {
    const int kr = t & 15, sel = t >> 4;
    const float* wr = W + (size_t)(kt * 16 + kr) * FOUT;
    const float* av = a + sel * FOUT;
    float s = 0.f;
    for (int n = 0; n < FOUT; ++n) s += wr[n] * av[n];
    wt[kr][sel] = s * 1.44269504f;
  }
  __syncthreads();
#pragma unroll
  for (int i = 0; i < 12; ++i) {
    const int idx = t + i * 256;  // within-kt offset < 3072
    const int e = idx & 7, n = (idx >> 3) & 31, r2 = idx >> 8;
    const int khb = r2 & 1, q = r2 >> 1;
    const int nf = q % 3, h = q / 3;
    const int k = khb * 8 + e;
    float v = nf < 2 ? wm[k][nf * 32 + n]
                     : (n == 0 ? wt[k][0] : (n == 1 ? wt[k][1] : 0.f));
    const unsigned short hi = f2bf(v);
    Bw[(size_t)kt * 3072 + idx] = (h == 0) ? hi : f2bf(v - bf2f(hi));
  }
}

// ---- K2: convert_x — x f32 -> hi/lo bf16 A-fragments ----
__global__ __launch_bounds__(256) void convert_x(const float* __restrict__ X,
                                                 unsigned short* __restrict__ xf) {
  const int f = blockIdx.x * 256 + threadIdx.x;  // < 524288
  const int r = f & 31, kh = (f >> 5) & 1, kt = (f >> 6) & 31, mw = f >> 11;
  const float* src = X + (size_t)(mw * 32 + r) * FIN + kt * 16 + kh * 8;
  const float4 v0 = *(const float4*)src;
  const float4 v1 = *(const float4*)(src + 4);
  const float vv[8] = {v0.x, v0.y, v0.z, v0.w, v1.x, v1.y, v1.z, v1.w};
  us8 vh, vl;
#pragma unroll
  for (int e = 0; e < 8; ++e) {
    const unsigned short hi = f2bf(vv[e]);
    vh[e] = hi;
    vl[e] = f2bf(vv[e] - bf2f(hi));
  }
  const size_t b0 = ((size_t)(mw * 32 + kt) * 4 + kh) * 256 + (size_t)r * 8;
  *(us8*)(xf + b0) = vh;
  *(us8*)(xf + b0 + 512) = vl;  // h stride = 512 shorts
}

// ---- K3: gemm_whm — Whm = x @ Wm (hi/lo 3-product MFMA) + s extraction ----
__global__ __launch_bounds__(192) void gemm_whm(const unsigned short* __restrict__ xf,
                                                const unsigned short* __restrict__ Bw,
                                                float* __restrict__ Whm,
                                                float* __restrict__ ssrc,
                                                float* __restrict__ sdst) {
  __shared__ float sred[32][2];
  const int mw = blockIdx.x;
  const int nf = threadIdx.x >> 6, lane = threadIdx.x & 63;
  const int l31 = lane & 31, kh = lane >> 5;
  f32x16 acc = (f32x16)(0.f);
  const unsigned short* ap = xf + ((size_t)(mw * 32) * 4 + kh) * 256 + l31 * 8;
  const unsigned short* bp = Bw + ((size_t)nf * 2 + kh) * 256 + l31 * 8;
#pragma unroll 4
  for (int kt = 0; kt < 32; ++kt) {
    const bf16x8 a_h = *(const bf16x8*)(ap + kt * 1024);
    const bf16x8 a_l = *(const bf16x8*)(ap + kt * 1024 + 512);
    const bf16x8 b_h = *(const bf16x8*)(bp + kt * 3072);
    const bf16x8 b_l = *(const bf16x8*)(bp + kt * 3072 + 1536);
    acc = __builtin_amdgcn_mfma_f32_32x32x16_bf16(a_h, b_h, acc, 0, 0, 0);
    acc = __builtin_amdgcn_mfma_f32_32x32x16_bf16(a_h, b_l, acc, 0, 0, 0);
    acc = __builtin_amdgcn_mfma_f32_32x32x16_bf16(a_l, b_h, acc, 0, 0, 0);
  }
  if (nf < 2) {
#pragma unroll
    for (int reg = 0; reg < 16; ++reg) {
      const int row = (reg & 3) + ((reg >> 2) << 3) + (kh << 2);
      Whm[(size_t)(mw * 32 + row) * FH + nf * 32 + l31] = acc[reg];
    }
  } else if (l31 < 2) {
#pragma unroll
    for (int reg = 0; reg < 16; ++reg) {
      const int row = (reg & 3) + ((reg >> 2) << 3) + (kh << 2);
      sred[row][l31] = acc[reg];
    }
  }
  __syncthreads();
  if (threadIdx.x < 32) {
    ssrc[mw * 32 + threadIdx.x] = sred[threadIdx.x][0];
    sdst[mw * 32 + threadIdx.x] = sred[threadIdx.x][1];
  }
}

// ---- K4: build_whb — Whm f32 -> Bg hi/lo B-fragments for gat_aggr ----
// Bg per jw (32 j): [h(2)][kc(2)][khb(2)][nf(2)][nn(32)][e(8)] = 4096 shorts.
__global__ __launch_bounds__(256) void build_whb(const float* __restrict__ Whm,
                                                 unsigned short* __restrict__ Bg) {
  const int idx = blockIdx.x * 256 + threadIdx.x;  // < 65536
  const int n = idx & 63, jo = idx >> 6;           // jo = j>>3 < 1024
  const int jw = jo >> 2, kc = (jo >> 1) & 1, khb = jo & 1;
  const int nf = n >> 5, nn = n & 31;
  us8 vh, vl;
#pragma unroll
  for (int e = 0; e < 8; ++e) {
    const float v = Whm[(size_t)(jo * 8 + e) * FH + n];
    const unsigned short hi = f2bf(v);
    vh[e] = hi;
    vl[e] = f2bf(v - bf2f(hi));
  }
  const size_t base =
      (size_t)jw * 4096 + (size_t)((kc * 2 + khb) * 2 + nf) * 256 + nn * 8;
  *(us8*)(Bg + base) = vh;           // h=0
  *(us8*)(Bg + base + 2048) = vl;    // h=1
}

// ---- K5: gat_aggr — B slice staged ONCE in LDS; barrier-free main loop ----
// grid 1024 = 32 bm x 32 bj; 512 thr / 8 waves; wave = 32 rows x 64 cols.
// 2 blocks/CU (64 KB LDS each). adj on vmcnt, B on lgkmcnt: decoupled.
#define GLL(G, L)                                                           \
  __builtin_amdgcn_global_load_lds(                                         \
      (const __attribute__((address_space(1))) unsigned int*)(G),           \
      (__attribute__((address_space(3))) unsigned int*)(L), 16, 0, 0)

#define GEN1(V, E, Q, SD)                         \
  {                                               \
    float tt = ss + (SD);                         \
    float lr = fmaxf(tt, 0.2f * tt);              \
    float pe = (Q) ? fastexp2(lr) : 1.0f;         \
    unsigned short hb = f2bf(pe);                 \
    V[E] = (short)hb;                             \
    dacc += bf2f(hb);                             \
  }
#define GEN8(V, QA, QB, SA, SB)                   \
  GEN1(V, 0, (QA).x, (SA).x)                      \
  GEN1(V, 1, (QA).y, (SA).y)                      \
  GEN1(V, 2, (QA).z, (SA).z)                      \
  GEN1(V, 3, (QA).w, (SA).w)                      \
  GEN1(V, 4, (QB).x, (SB).x)                      \
  GEN1(V, 5, (QB).y, (SB).y)                      \
  GEN1(V, 6, (QB).z, (SB).z)                      \
  GEN1(V, 7, (QB).w, (SB).w)

__global__ __launch_bounds__(512, 4) void gat_aggr(
    const int* __restrict__ adj, const float* __restrict__ ssrc_g,
    const float* __restrict__ sdst_g, const unsigned short* __restrict__ Bg,
    unsigned short* __restrict__ Upb, float* __restrict__ Dp) {
  __shared__ unsigned short lbuf[STEPS * 4096];  // 64 KB: whole bj B slice
  const int bid = blockIdx.x;
  const int bj = bid & 31, bm = bid >> 5;
  const int wv = threadIdx.x >> 6, lane = threadIdx.x & 63;
  const int l31 = lane & 31, kh = lane >> 5;
  const int rbase = bm * 256;
  const int myrow = rbase + wv * 32 + l31;
  const int jb = bj * JCHUNK;
  const float ss = ssrc_g[myrow];
  const int* arow = adj + (size_t)myrow * NN + jb + kh * 8;
  const float* sdp = sdst_g + jb + kh * 8;

  // ---- prologue: stage whole 64 KB B slice + adj t=0 regs ----
  {
    const unsigned short* gs = Bg + (size_t)bj * (STEPS * 4096) +
                               (size_t)(wv * 8) * 512 + lane * 8;
#pragma unroll
    for (int c = 0; c < 8; ++c) GLL(gs + c * 512, &lbuf[(wv * 8 + c) * 512]);
  }
  int4 ajA0 = *(const int4*)(arow);
  int4 ajA1 = *(const int4*)(arow + 4);
  int4 ajA2 = *(const int4*)(arow + 16);
  int4 ajA3 = *(const int4*)(arow + 20);
  int4 ajB0, ajB1, ajB2, ajB3;

  f32x16 acc0 = (f32x16)(0.f), acc1 = (f32x16)(0.f);
  float dacc = 0.f;
  __syncthreads();  // B slice landed; only barrier in the kernel

  const unsigned short* lb0 = &lbuf[kh * 512 + l31 * 8];

#define STEP(T, C0, C1, C2, C3, N0, N1, N2, N3)                               \
  {                                                                           \
    if ((T) + 1 < STEPS) {                                                    \
      N0 = *(const int4*)(arow + ((T) + 1) * 32);                             \
      N1 = *(const int4*)(arow + ((T) + 1) * 32 + 4);                         \
      N2 = *(const int4*)(arow + ((T) + 1) * 32 + 16);                        \
      N3 = *(const int4*)(arow + ((T) + 1) * 32 + 20);                        \
    }                                                                         \
    const unsigned short* tb = lb0 + (size_t)(T) * 4096;                      \
    const bf16x8 b00 = *(const bf16x8*)(tb);          /* kc0 h0 nf0 */        \
    const bf16x8 b01 = *(const bf16x8*)(tb + 2048);   /* kc0 h1 nf0 */        \
    const bf16x8 b02 = *(const bf16x8*)(tb + 256);    /* kc0 h0 nf1 */        \
    const bf16x8 b03 = *(const bf16x8*)(tb + 2304);   /* kc0 h1 nf1 */        \
    const bf16x8 b10 = *(const bf16x8*)(tb + 1024);   /* kc1 h0 nf0 */        \
    const bf16x8 b11 = *(const bf16x8*)(tb + 3072);   /* kc1 h1 nf0 */        \
    const bf16x8 b12 = *(const bf16x8*)(tb + 1280);   /* kc1 h0 nf1 */        \
    const bf16x8 b13 = *(const bf16x8*)(tb + 3328);   /* kc1 h1 nf1 */        \
    bf16x8 af0, af1;                                                          \
    {                                                                         \
      const float4 sA0 = *(const float4*)(sdp + (T) * 32);                    \
      const float4 sB0 = *(const float4*)(sdp + (T) * 32 + 4);                \
      const float4 sA1 = *(const float4*)(sdp + (T) * 32 + 16);               \
      const float4 sB1 = *(const float4*)(sdp + (T) * 32 + 20);               \
      GEN8(af0, C0, C1, sA0, sB0);                                            \
      GEN8(af1, C2, C3, sA1, sB1);                                            \
    }                                                                         \
    acc0 = __builtin_amdgcn_mfma_f32_32x32x16_bf16(af0, b00, acc0, 0, 0, 0);  \
    acc0 = __builtin_amdgcn_mfma_f32_32x32x16_bf16(af0, b01, acc0, 0, 0, 0);  \
    acc1 = __builtin_amdgcn_mfma_f32_32x32x16_bf16(af0, b02, acc1, 0, 0, 0);  \
    acc1 = __builtin_amdgcn_mfma_f32_32x32x16_bf16(af0, b03, acc1, 0, 0, 0);  \
    acc0 = __builtin_amdgcn_mfma_f32_32x32x16_bf16(af1, b10, acc0, 0, 0, 0);  \
    acc0 = __builtin_amdgcn_mfma_f32_32x32x16_bf16(af1, b11, acc0, 0, 0, 0);  \
    acc1 = __builtin_amdgcn_mfma_f32_32x32x16_bf16(af1, b12, acc1, 0, 0, 0);  \
    acc1 = __builtin_amdgcn_mfma_f32_32x32x16_bf16(af1, b13, acc1, 0, 0, 0);  \
  }

#pragma unroll 1
  for (int it = 0; it < STEPS / 2; ++it) {
    STEP(2 * it, ajA0, ajA1, ajA2, ajA3, ajB0, ajB1, ajB2, ajB3)
    STEP(2 * it + 1, ajB0, ajB1, ajB2, ajB3, ajA0, ajA1, ajA2, ajA3)
  }
#undef STEP

  // ---- D: lanes l, l+32 hold complementary kh halves of same row ----
  dacc += __shfl_xor(dacc, 32);
  if (lane < 32) Dp[(size_t)bj * NN + myrow] = dacc;

  // ---- U: C/D layout col=lane&31, row=(reg&3)+8*(reg>>2)+4*(lane>>5) ----
  unsigned short* ub = Upb + ((size_t)bj * NN + rbase + wv * 32) * FH;
#pragma unroll
  for (int reg = 0; reg < 16; ++reg) {
    const int rr = (reg & 3) + ((reg >> 2) << 3) + (kh << 2);
    ub[(size_t)rr * FH + l31] = f2bf(acc0[reg]);
    ub[(size_t)rr * FH + 32 + l31] = f2bf(acc1[reg]);
  }
}

// ---- K6: finalize — combine j-splits, divide ----
__global__ __launch_bounds__(256) void finalize(const unsigned short* __restrict__ Upb,
                                                const float* __restrict__ Dp,
                                                float* __restrict__ out) {
  const int idx = blockIdx.x * 256 + threadIdx.x;  // < 8192*64
  const int i = idx >> 6;
  float u = 0.f, d = 0.f;
#pragma unroll
  for (int s = 0; s < JSPLIT; ++s) {
    d += Dp[(size_t)s * NN + i];
    u += bf2f(Upb[(size_t)s * NN * FH + idx]);
  }
  out[idx] = u / d;
}

extern "C" void kernel_launch(void* const* d_in, const int* in_sizes, int n_in,
                              void* d_out, int out_size, void* d_ws, size_t ws_size,
                              hipStream_t stream) {
  const float* x = (const float*)d_in[0];
  const int* adj = (const int*)d_in[1];
  const float* W = (const float*)d_in[2];
  const float* a = (const float*)d_in[3];
  char* ws = (char*)d_ws;

  // ws layout (~37.4 MB):
  //   xf   [0, 16 MB)   bf16 hi/lo x-fragments (dead after gemm_whm)
  //   Upb  [0, 32 MB)   bf16 U partials (32 splits) -- OVERLAPS xf
  //   Bg   [32, 34 MB)  bf16 hi/lo Whm B-fragments
  //   Whm  [34, 36 MB)  f32 head-mean of Wh
  //   Bw   [36 MB, +192 KB); ssrc +256K; sdst +288K; Dp +320K (1 MB)
  unsigned short* xf = (unsigned short*)ws;
  unsigned short* Upb = (unsigned short*)ws;
  unsigned short* Bg = (unsigned short*)(ws + ((size_t)32 << 20));
  float* Whm = (float*)(ws + ((size_t)34 << 20));
  unsigned short* Bw = (unsigned short*)(ws + ((size_t)36 << 20));
  float* ssrc = (float*)(ws + ((size_t)36 << 20) + (256u << 10));
  float* sdst = (float*)(ws + ((size_t)36 << 20) + (288u << 10));
  float* Dp = (float*)(ws + ((size_t)36 << 20) + (320u << 10));
  float* out = (float*)d_out;

  prep_small<<<32, 256, 0, stream>>>(W, a, Bw);
  convert_x<<<2048, 256, 0, stream>>>(x, xf);
  gemm_whm<<<256, 192, 0, stream>>>(xf, Bw, Whm, ssrc, sdst);
  build_whb<<<65536 / 256, 256, 0, stream>>>(Whm, Bg);
  gat_aggr<<<32 * JSPLIT, 512, 0, stream>>>(adj, ssrc, sdst, Bg, Upb, Dp);
  finalize<<<NN * FH / 256, 256, 0, stream>>>(Upb, Dp, out);
}